// Round 12
// baseline (459.939 us; speedup 1.0000x reference)
//
#include <hip/hip_runtime.h>
#include <hip/hip_bf16.h>

typedef unsigned short ushortT;
typedef __attribute__((ext_vector_type(8))) short v8s;
typedef __attribute__((ext_vector_type(4))) float v4f;

// Problem sizes (fixed by reference)
#define B_N   8192
#define S_N   512
#define F_N   64
#define R_N   4096
#define D_N   256
#define T_N   16
#define SF_N  (S_N * F_N)

#define GR    16            // rows per group (MFMA M-tile)
#define NBLK  256           // persistent: 1 block/CU; 32 rows (2 groups) per block

__device__ __forceinline__ ushortT f2bf(float x) {
  __hip_bfloat16 b = __float2bfloat16(x);
  return *(ushortT*)&b;
}
__device__ __forceinline__ float bf2f(ushortT u) {
  __hip_bfloat16 b = *(__hip_bfloat16*)&u;
  return __bfloat162float(b);
}
__device__ __forceinline__ void splitHL8(const float* v, v8s& h8, v8s& l8) {
  union { short s[8]; v8s v; } H, L;
#pragma unroll
  for (int j = 0; j < 8; ++j) {
    const float x = v[j];
    const ushortT hb = f2bf(x);
    H.s[j] = (short)hb;
    L.s[j] = (short)f2bf(x - bf2f(hb));
  }
  h8 = H.v; l8 = L.v;
}

// ---- K0: reg -> frag-swizzled bf16 H/L + rsqh (verified R8-R11) --------------
// regHs[((g*8 + k0)*64 + lane)*8 + j] = reg[g*16 + (lane&15)][k0*32 + (lane>>4)*8 + j]
__global__ __launch_bounds__(256) void k_prep(const float* __restrict__ reg,
                                              ushortT* __restrict__ regHs,
                                              ushortT* __restrict__ regLs,
                                              float* __restrict__ rsqh) {
  const int g = blockIdx.x;
  const int t = threadIdx.x;
  const int lane = t & 63;
  const int q = t >> 6;
  const int n16 = lane & 15;
  const int kg = lane >> 4;
  const int row = g * 16 + n16;
#pragma unroll
  for (int h = 0; h < 2; ++h) {
    const int k0 = q + h * 4;
    float v[8];
    *(float4*)&v[0] = *(const float4*)&reg[(size_t)row * D_N + k0 * 32 + kg * 8];
    *(float4*)&v[4] = *(const float4*)&reg[(size_t)row * D_N + k0 * 32 + kg * 8 + 4];
    v8s h8, l8;
    splitHL8(v, h8, l8);
    const size_t o = ((size_t)(g * 8 + k0) * 64 + lane) * 8;
    *(v8s*)&regHs[o] = h8;
    *(v8s*)&regLs[o] = l8;
  }
  const int r16 = t >> 4, seg = t & 15;
  const float* rp = &reg[(size_t)(g * 16 + r16) * D_N + seg * 16];
  float s = 0.f;
#pragma unroll
  for (int j = 0; j < 4; ++j) {
    const float4 v = *(const float4*)&rp[j * 4];
    s += v.x * v.x + v.y * v.y + v.z * v.z + v.w * v.w;
  }
#pragma unroll
  for (int m = 8; m >= 1; m >>= 1) s += __shfl_xor(s, m);
  if (seg == 0) rsqh[g * 16 + r16] = 0.5f * s;
}

// ---- Fused, producer/consumer pipelined over 2 groups of 16 rows ----
__global__ __launch_bounds__(512, 2) void k_fused(const float* __restrict__ x,
                                                  const float* __restrict__ W,
                                                  const float* __restrict__ bias,
                                                  const float* __restrict__ reg,
                                                  const ushortT* __restrict__ regHs,
                                                  const ushortT* __restrict__ regLs,
                                                  const float* __restrict__ rsqh,
                                                  float* __restrict__ out,
                                                  float* __restrict__ lossPart) {
  __shared__ __align__(16) float xm[2][GR][68];      // mean scratch     8.7 KB
  __shared__ __align__(16) ushortT xeHs[2][4096];    // xe H frags       16 KB
  __shared__ __align__(16) ushortT xeLs[2][4096];    // xe L frags       16 KB
  __shared__ float swv[8][GR];
  __shared__ int   swi[8][GR];
  __shared__ float srowloss[2][GR];
  __shared__ int   sbi[GR];

  const int t = threadIdx.x;
  const int w = t >> 6;       // wave 0..7
  const int lane = t & 63;
  const int bm0 = blockIdx.x * (2 * GR);
  const int n16 = lane & 15;
  const int kg = lane >> 4;

  // stream one 128-KB row (contiguous, NT, 16 x 1KB in flight) -> xm[g][lr]
  auto stream_row = [&](int grow, int g, int lr) {
    const v4f* xw = (const v4f*)(x + (size_t)grow * SF_N);
    float c0 = 0.f, c1 = 0.f, c2 = 0.f, c3 = 0.f;
#pragma unroll 1
    for (int i0 = 0; i0 < 128; i0 += 16) {
      v4f vv[16];
#pragma unroll
      for (int u = 0; u < 16; ++u)
        vv[u] = __builtin_nontemporal_load(&xw[(size_t)(i0 + u) * 64 + lane]);
#pragma unroll
      for (int u = 0; u < 16; ++u) {
        c0 += vv[u][0]; c1 += vv[u][1]; c2 += vv[u][2]; c3 += vv[u][3];
      }
    }
    c0 += __shfl_xor(c0, 16); c1 += __shfl_xor(c1, 16);
    c2 += __shfl_xor(c2, 16); c3 += __shfl_xor(c3, 16);
    c0 += __shfl_xor(c0, 32); c1 += __shfl_xor(c1, 32);
    c2 += __shfl_xor(c2, 32); c3 += __shfl_xor(c3, 32);
    if (lane < 16) {
      const float inv = 1.0f / (float)S_N;
      const int f4 = lane * 4;
      xm[g][lr][f4 + 0] = c0 * inv;
      xm[g][lr][f4 + 1] = c1 * inv;
      xm[g][lr][f4 + 2] = c2 * inv;
      xm[g][lr][f4 + 3] = c3 * inv;
    }
  };

  // projection of group g -> H/L frag LDS (all 512 threads)
  auto proj = [&](int g) {
    const int prow = t >> 5;   // 0..15
    const int dgr = t & 31;    // d = dgr*8 .. +7
    float pv[8];
#pragma unroll
    for (int dd = 0; dd < 8; ++dd) {
      const int d = dgr * 8 + dd;
      float p = bias[d];
#pragma unroll
      for (int k4 = 0; k4 < 16; ++k4) {
        const float4 wv = *(const float4*)&W[(size_t)d * F_N + k4 * 4];
        const float4 xv = *(const float4*)&xm[g][prow][k4 * 4];
        p = fmaf(wv.x, xv.x, p); p = fmaf(wv.y, xv.y, p);
        p = fmaf(wv.z, xv.z, p); p = fmaf(wv.w, xv.w, p);
      }
      pv[dd] = p;
    }
    const int d0 = dgr * 8;
    const int k0 = d0 >> 5, kgp = (d0 >> 3) & 3;
    v8s h8, l8;
    splitHL8(pv, h8, l8);
    const int idx = (k0 * 64 + kgp * 16 + prow) * 8;
    *(v8s*)&xeHs[g][idx] = h8;
    *(v8s*)&xeLs[g][idx] = l8;
  };

  // score group g over col-groups [gbase, gbase+4*iters), write strip
  auto score = [&](int g, int gbase, int iters, int strip) {
    float bvj[4];
    int bij[4];
#pragma unroll
    for (int j = 0; j < 4; ++j) { bvj[j] = 3.4e38f; bij[j] = 0; }
    for (int c = 0; c < iters; ++c) {
      const int g0 = gbase + c * 4;
      v4f acc[4];
#pragma unroll
      for (int ni = 0; ni < 4; ++ni) acc[ni] = (v4f){0.f, 0.f, 0.f, 0.f};
      const ushortT* BH = regHs + (size_t)g0 * 4096 + lane * 8;
      const ushortT* BL = regLs + (size_t)g0 * 4096 + lane * 8;
#pragma unroll
      for (int k0 = 0; k0 < 8; ++k0) {
        const int ao = (k0 * 64 + lane) * 8;
        const v8s ah = *(const v8s*)&xeHs[g][ao];
        const v8s al = *(const v8s*)&xeLs[g][ao];
#pragma unroll
        for (int ni = 0; ni < 4; ++ni) {
          const v8s bh = *(const v8s*)&BH[(size_t)(ni * 8 + k0) * 512];
          const v8s bl = *(const v8s*)&BL[(size_t)(ni * 8 + k0) * 512];
          acc[ni] = __builtin_amdgcn_mfma_f32_16x16x32_bf16(ah, bh, acc[ni], 0, 0, 0);
          acc[ni] = __builtin_amdgcn_mfma_f32_16x16x32_bf16(ah, bl, acc[ni], 0, 0, 0);
          acc[ni] = __builtin_amdgcn_mfma_f32_16x16x32_bf16(al, bh, acc[ni], 0, 0, 0);
        }
      }
#pragma unroll
      for (int ni = 0; ni < 4; ++ni) {   // ascending col groups -> lowest idx on ties
        const float rq = rsqh[(g0 + ni) * 16 + n16];
        const int col = (g0 + ni) * 16 + n16;
#pragma unroll
        for (int j = 0; j < 4; ++j) {    // row = kg*4 + j
          const float s = rq - acc[ni][j];
          if (s < bvj[j]) { bvj[j] = s; bij[j] = col; }
        }
      }
    }
#pragma unroll
    for (int j = 0; j < 4; ++j) {
      float v = bvj[j];
      int ix = bij[j];
#pragma unroll
      for (int m = 8; m >= 1; m >>= 1) {
        const float ov = __shfl_xor(v, m);
        const int oi = __shfl_xor(ix, m);
        if (ov < v || (ov == v && oi < ix)) { v = ov; ix = oi; }
      }
      if (n16 == 0) { swv[strip][kg * 4 + j] = v; swi[strip][kg * 4 + j] = ix; }
    }
  };

  // gather + emit 16 tokens/row + per-row loss, group g (uses sbi)
  auto emitg = [&](int g) {
    const int prow = t >> 5;   // 0..15
    const int seg = t & 31;    // d = seg*8 .. +7
    const int d8 = seg * 8;
    const int gr = bm0 + g * GR + prow;
    const int ix = sbi[prow];
    __align__(16) float sel[8];  // static indices only
    *(float4*)&sel[0] = *(const float4*)&reg[(size_t)ix * D_N + d8];
    *(float4*)&sel[4] = *(const float4*)&reg[(size_t)ix * D_N + d8 + 4];
#pragma unroll
    for (int tt = 0; tt < T_N; ++tt) {
      float* op = &out[((size_t)gr * T_N + tt) * D_N + d8];
      *(float4*)&op[0] = *(float4*)&sel[0];
      *(float4*)&op[4] = *(float4*)&sel[4];
    }
    const int k0 = d8 >> 5, kgp = (d8 >> 3) & 3;
    const int idx = (k0 * 64 + kgp * 16 + prow) * 8;
    const v8s vh = *(const v8s*)&xeHs[g][idx];
    const v8s vl = *(const v8s*)&xeLs[g][idx];
    float p = 0.f;
#pragma unroll
    for (int j = 0; j < 8; ++j) {
      const float xej = bf2f((ushortT)vh[j]) + bf2f((ushortT)vl[j]);
      const float dd = xej - sel[j];
      p = fmaf(dd, dd, p);
    }
#pragma unroll
    for (int m = 16; m >= 1; m >>= 1) p += __shfl_xor(p, m);
    if (seg == 0) srowloss[g][prow] = p;
  };

  // ---------------- pipeline ----------------
  // P0: all 8 waves stream group 0 (2 rows each)
  stream_row(bm0 + 2 * w + 0, 0, 2 * w + 0);
  stream_row(bm0 + 2 * w + 1, 0, 2 * w + 1);
  __syncthreads();
  proj(0);
  __syncthreads();

  // S0: waves 0-3 stream group 1 (4 rows each) || waves 4-7 score group 0 (1024 cols each)
  if (w < 4) {
#pragma unroll 1
    for (int rr = 0; rr < 4; ++rr)
      stream_row(bm0 + GR + w * 4 + rr, 1, w * 4 + rr);
  } else {
    score(0, (w - 4) * 64, 16, w - 4);
  }
  __syncthreads();

  // E0a: block argmin group 0 (4 strips, ascending cols) ; proj group 1
  if (t < GR) {
    float bv = swv[0][t];
    int bi = swi[0][t];
#pragma unroll
    for (int s = 1; s < 4; ++s) {
      const float ov = swv[s][t];
      const int oi = swi[s][t];
      if (ov < bv || (ov == bv && oi < bi)) { bv = ov; bi = oi; }
    }
    sbi[t] = bi;
  }
  proj(1);
  __syncthreads();

  // E0b: emit group 0 (writes drain under MFMA) ; then all 8 waves score group 1
  emitg(0);
  score(1, w * 32, 8, w);
  __syncthreads();

  // E1: block argmin group 1 (8 strips)
  if (t < GR) {
    float bv = swv[0][t];
    int bi = swi[0][t];
#pragma unroll
    for (int s = 1; s < 8; ++s) {
      const float ov = swv[s][t];
      const int oi = swi[s][t];
      if (ov < bv || (ov == bv && oi < bi)) { bv = ov; bi = oi; }
    }
    sbi[t] = bi;
  }
  __syncthreads();

  emitg(1);
  __syncthreads();

  if (t == 0) {
    float lp = 0.f;
#pragma unroll
    for (int r = 0; r < GR; ++r) lp += srowloss[0][r] + srowloss[1][r];
    lossPart[blockIdx.x] = lp;
  }
}

// ---- K2: loss = sum(parts)/B ----
__global__ __launch_bounds__(256) void k_loss(const float* __restrict__ lossPart,
                                              float* __restrict__ out) {
  __shared__ float ws4[4];
  const int t = threadIdx.x;
  float s = lossPart[t];  // exactly 256 parts
#pragma unroll
  for (int m = 32; m >= 1; m >>= 1) s += __shfl_xor(s, m);
  if ((t & 63) == 0) ws4[t >> 6] = s;
  __syncthreads();
  if (t == 0)
    out[(size_t)B_N * T_N * D_N] = (ws4[0] + ws4[1] + ws4[2] + ws4[3]) / (float)B_N;
}

extern "C" void kernel_launch(void* const* d_in, const int* in_sizes, int n_in,
                              void* d_out, int out_size, void* d_ws, size_t ws_size,
                              hipStream_t stream) {
  const float* x    = (const float*)d_in[0];
  const float* W    = (const float*)d_in[1];
  const float* bias = (const float*)d_in[2];
  const float* reg  = (const float*)d_in[3];
  float* out = (float*)d_out;

  // workspace: all regions fully rewritten every call (~4 MB)
  ushortT* regHs = (ushortT*)d_ws;                      // 2 MB, frag-swizzled
  ushortT* regLs = regHs + (size_t)R_N * D_N;           // 2 MB
  float*   rsqh  = (float*)(regLs + (size_t)R_N * D_N); // 4096
  float*   lossPart = rsqh + R_N;                       // 256

  k_prep<<<dim3(R_N / 16), dim3(256), 0, stream>>>(reg, regHs, regLs, rsqh);
  k_fused<<<dim3(NBLK), dim3(512), 0, stream>>>(x, W, bias, reg, regHs, regLs, rsqh,
                                                out, lossPart);
  k_loss<<<dim3(1), dim3(256), 0, stream>>>(lossPart, out);
}